// Round 2
// baseline (156.375 us; speedup 1.0000x reference)
//
#include <hip/hip_runtime.h>

// mus = W2·tanh(W1·x + b1) + b2, logvars = 0, banded DAG: parents(n) = n-8..n-1.
//
// Round-2 design: thread = batch row, 4 threads per row (16 nodes each).
//  - parent gather = sliding register window over the thread's own gt row
//    (parents are always the previous 8 node values) -> zero shuffles
//  - node loop is wave-uniform -> weight loads are scalar (s_load, K$/L2),
//    zero VGPR cost, zero VALU cost
//  - layer1 packed over parent pairs (v_pk_fma_f32; W1[n][h][p],[p+1] are
//    memory-adjacent -> SGPR-pair operands)
//  - tanh via Pade(5,4) + clamp(+-3.5), identical numerics to round 1
//    (absmax was 0.0078 vs threshold 0.0273)
//  - grid 2048x256 = 8192 waves -> 8 waves/SIMD grid occupancy

#define BATCH 131072
#define NODES 64
#define HID   16
#define TPB   256

typedef float v2 __attribute__((ext_vector_type(2)));

__device__ __forceinline__ v2 tanh2(v2 x) {
    const v2 hi = {  3.5f,  3.5f };
    const v2 lo = { -3.5f, -3.5f };
    x = __builtin_elementwise_min(x, hi);
    x = __builtin_elementwise_max(x, lo);
    v2 x2  = x * x;
    v2 num = x2 * (x2 + 105.f) + 945.f;          // 945 + 105 x^2 + x^4
    v2 den = x2 * (x2 * 15.f + 420.f) + 945.f;   // 945 + 420 x^2 + 15 x^4
    v2 r;
    r.x = __builtin_amdgcn_rcpf(den.x);
    r.y = __builtin_amdgcn_rcpf(den.y);
    return x * num * r;
}

struct Wts { const float* w1; const float* b1; const float* w2; const float* b2; };

// One node: mu = W2[n]·tanh(W1[n]·x + b1[n]) + b2[n].
// xp[4] = parent values paired {x0,x1},{x2,x3},{x4,x5},{x6,x7}.
// All weight addresses are wave-uniform -> scalar loads.
__device__ __forceinline__ float node_mu(const v2 xp[4], int n, Wts w) {
    const float* __restrict__ wp  = w.w1 + n * (HID * 8);
    const float* __restrict__ b1p = w.b1 + n * HID;
    const float* __restrict__ w2p = w.w2 + n * HID;
    v2 mu2 = {0.f, 0.f};
    #pragma unroll 2
    for (int h2 = 0; h2 < 8; ++h2) {
        const float* __restrict__ w0 = wp + h2 * 16;   // rows h=2*h2, 2*h2+1
        v2 A = {0.f, 0.f}, B = {0.f, 0.f};
        #pragma unroll
        for (int p2 = 0; p2 < 4; ++p2) {
            v2 wA = { w0[2 * p2],     w0[2 * p2 + 1] };     // adjacent -> s-pair
            v2 wB = { w0[8 + 2 * p2], w0[8 + 2 * p2 + 1] };
            A = __builtin_elementwise_fma(xp[p2], wA, A);
            B = __builtin_elementwise_fma(xp[p2], wB, B);
        }
        v2 h;
        h.x = A.x + A.y + b1p[2 * h2];
        h.y = B.x + B.y + b1p[2 * h2 + 1];
        v2 t = tanh2(h);
        v2 w2v = { w2p[2 * h2], w2p[2 * h2 + 1] };
        mu2 = __builtin_elementwise_fma(t, w2v, mu2);
    }
    return mu2.x + mu2.y + w.b2[n];
}

__device__ __forceinline__ void unpack8(float* d, float4 a, float4 b) {
    d[0] = a.x; d[1] = a.y; d[2] = a.z; d[3] = a.w;
    d[4] = b.x; d[5] = b.y; d[6] = b.z; d[7] = b.w;
}

// 8 nodes nbase..nbase+7, each with full 8-parent window drawn from prev/cur.
__device__ __forceinline__ void do_block8(const float prev[8], const float cur[8],
                                          int nbase, float m[8], Wts w) {
    #pragma unroll
    for (int j = 0; j < 8; ++j) {
        v2 xp[4];
        #pragma unroll
        for (int p2 = 0; p2 < 4; ++p2) {
            // parent slot p of node nbase+j = node value (nbase+j-8+p)
            float a = (j + 2 * p2     < 8) ? prev[j + 2 * p2]     : cur[j + 2 * p2 - 8];
            float c = (j + 2 * p2 + 1 < 8) ? prev[j + 2 * p2 + 1] : cur[j + 2 * p2 + 1 - 8];
            v2 t = { a, c };
            xp[p2] = t;
        }
        m[j] = node_mu(xp, nbase + j, w);
    }
}

__device__ __forceinline__ void store8(float* p, const float m[8]) {
    float4 s0 = { m[0], m[1], m[2], m[3] };
    float4 s1 = { m[4], m[5], m[6], m[7] };
    ((float4*)p)[0] = s0;
    ((float4*)p)[1] = s1;
}

__global__ __launch_bounds__(TPB, 4)
void prior_kernel(const float* __restrict__ gt, const float* __restrict__ W1,
                  const float* __restrict__ b1, const float* __restrict__ W2,
                  const float* __restrict__ b2, float* __restrict__ out)
{
    const int g = blockIdx.x * TPB + threadIdx.x;
    const int q = blockIdx.x >> 9;          // quarter index 0..3 (uniform per block)
    const int b = g & (BATCH - 1);          // batch row
    const float4* gp = (const float4*)(gt + (size_t)b * NODES);
    float* outm = out + (size_t)b * NODES;
    float* outv = out + (size_t)BATCH * NODES + (size_t)b * NODES;
    Wts w = { W1, b1, W2, b2 };

    float c0[8], c1[8], cm1[8], m[8];

    if (q == 0) {
        // nodes 0..15: chunk0 (nodes 0-7) + chunk1 (nodes 8-15)
        float4 A0 = gp[0], A1 = gp[1], A2 = gp[2], A3 = gp[3];
        unpack8(c0, A0, A1);
        unpack8(c1, A2, A3);
        // nodes 0..7: active parent slots p<n map to node p -> x[p] = c0[p];
        // slots p>=n have W1 zeroed by in_mask, any value is fine.
        v2 xp0[4] = { { A0.x, A0.y }, { A0.z, A0.w }, { A1.x, A1.y }, { A1.z, A1.w } };
        #pragma unroll
        for (int j = 0; j < 8; ++j) m[j] = node_mu(xp0, j, w);
        store8(outm, m);
        do_block8(c0, c1, 8, m, w);
        store8(outm + 8, m);
    } else {
        const int k0 = 2 * q;               // first 8-node chunk of this quarter
        float4 P0 = gp[2 * k0 - 2], P1 = gp[2 * k0 - 1];
        float4 A0 = gp[2 * k0],     A1 = gp[2 * k0 + 1];
        float4 A2 = gp[2 * k0 + 2], A3 = gp[2 * k0 + 3];
        unpack8(cm1, P0, P1);
        unpack8(c0, A0, A1);
        unpack8(c1, A2, A3);
        do_block8(cm1, c0, 16 * q, m, w);
        store8(outm + 16 * q, m);
        do_block8(c0, c1, 16 * q + 8, m, w);
        store8(outm + 16 * q + 8, m);
    }

    // logvars = 0
    float4 z = { 0.f, 0.f, 0.f, 0.f };
    float4* ov = (float4*)(outv + 16 * q);
    ov[0] = z; ov[1] = z; ov[2] = z; ov[3] = z;
}

extern "C" void kernel_launch(void* const* d_in, const int* in_sizes, int n_in,
                              void* d_out, int out_size, void* d_ws, size_t ws_size,
                              hipStream_t stream)
{
    const float* gt = (const float*)d_in[0];
    const float* W1 = (const float*)d_in[1];
    const float* b1 = (const float*)d_in[2];
    const float* W2 = (const float*)d_in[3];
    const float* b2 = (const float*)d_in[4];
    float* out = (float*)d_out;

    prior_kernel<<<4 * BATCH / TPB, TPB, 0, stream>>>(gt, W1, b1, W2, b2, out);
}